// Round 4
// baseline (303.272 us; speedup 1.0000x reference)
//
#include <hip/hip_runtime.h>
#include <cstdint>
#include <cstddef>

#define BS   8
#define C    256
#define C2   128
#define NPIX 4096

typedef unsigned short u16;
typedef unsigned int   u32;
typedef __bf16 bf16_t;
typedef bf16_t bf16x8 __attribute__((ext_vector_type(8)));
typedef float  f32x16 __attribute__((ext_vector_type(16)));

#define RCP_LN2 1.4426950408889634f

__device__ __forceinline__ u16 f2bf(float f) {
    union { float ff; u32 i; } x; x.ff = f;
    u32 r = x.i + 0x7fffu + ((x.i >> 16) & 1u);  // RNE
    return (u16)(r >> 16);
}
__device__ __forceinline__ float bf2f(u16 h) {
    union { u32 i; float f; } x; x.i = (u32)h << 16; return x.f;
}
__device__ __forceinline__ u32 pk2(u16 a, u16 b) { return (u32)a | ((u32)b << 16); }

// ---------------- W pre-split: fragment-major hi/lo ------------------------
// W[o][c] fp32 -> Wh/Wl[c8*O + o][8] bf16.  W = Wh + Wl exact to ~2^-17.
// Wq (z=0) is pre-scaled by 1/ln2 so attention can use exp2 directly.
__global__ __launch_bounds__(256)
void prep_w(const float* __restrict__ Wq, const float* __restrict__ Wk,
            const float* __restrict__ Wv,
            u16* __restrict__ qh, u16* __restrict__ ql,
            u16* __restrict__ kh, u16* __restrict__ kl,
            u16* __restrict__ vh, u16* __restrict__ vl) {
    const int z = blockIdx.y;                       // 0=q 1=k 2=v
    const int O = (z == 2) ? C : C2;                // O == CIN
    const int npair = O * O / 8;
    const int idx = blockIdx.x * 256 + threadIdx.x;
    if (idx >= npair) return;
    const int o  = idx & (O - 1);
    const int c8 = idx >> ((z == 2) ? 8 : 7);
    const float* src = (z == 0) ? Wq : (z == 1) ? Wk : Wv;
    u16* oh = (z == 0) ? qh : (z == 1) ? kh : vh;
    u16* ol = (z == 0) ? ql : (z == 1) ? kl : vl;
    const float scale = (z == 0) ? RCP_LN2 : 1.0f;
    u16 h[8], l[8];
    #pragma unroll
    for (int j = 0; j < 8; ++j) {
        const float f = src[(size_t)o * O + c8 * 8 + j] * scale;
        h[j] = f2bf(f);
        l[j] = f2bf(f - bf2f(h[j]));
    }
    *(uint4*)(oh + (size_t)idx * 8) =
        make_uint4(pk2(h[0], h[1]), pk2(h[2], h[3]), pk2(h[4], h[5]), pk2(h[6], h[7]));
    *(uint4*)(ol + (size_t)idx * 8) =
        make_uint4(pk2(l[0], l[1]), pk2(l[2], l[3]), pk2(l[4], l[5]), pk2(l[6], l[7]));
}

// ---------------- fused projections: z=0 Q, z=1 K, z=2/3 V n-halves --------
__global__ __launch_bounds__(256, 4)
void proj_all(const u16* __restrict__ wqh, const u16* __restrict__ wql,
              const u16* __restrict__ wkh, const u16* __restrict__ wkl,
              const u16* __restrict__ wvh, const u16* __restrict__ wvl,
              const float* __restrict__ bq, const float* __restrict__ bk,
              const float* __restrict__ bv,
              const float* __restrict__ a2, const float* __restrict__ a1,
              const float* __restrict__ motion,
              u16* __restrict__ qout, u16* __restrict__ kout,
              u16* __restrict__ vout) {
    __shared__ __align__(16) u16 Xb[16][64][8];   // 16 KB (V path: [32][32][8])
    const int t  = threadIdx.x;
    const int w  = t >> 6;
    const int li = t & 31;
    const int hs = (t >> 5) & 1;
    const int z  = blockIdx.z;
    const int b  = blockIdx.y;

    if (z < 2) {
        // ---------------- Q / K : out [b][n][128] --------------------------
        const u16* wh = z ? wkh : wqh;
        const u16* wl = z ? wkl : wql;
        const float* bias = z ? bk : bq;
        const float* x    = z ? a1 : a2;
        u16* out          = z ? kout : qout;
        const int n0 = blockIdx.x * 64;
        {
            const int sn = t & 63;
            const float* xb = x + (size_t)b * C2 * NPIX + n0 + sn;
            #pragma unroll
            for (int q = 0; q < 4; ++q) {
                const int c8 = q * 4 + w;
                union { bf16_t e[8]; uint4 u4; } cv;
                #pragma unroll
                for (int j = 0; j < 8; ++j)
                    cv.e[j] = (bf16_t)xb[(size_t)(c8 * 8 + j) * NPIX];
                *(uint4*)&Xb[c8][sn][0] = cv.u4;
            }
        }
        __syncthreads();

        f32x16 acc[2];
        #pragma unroll
        for (int nt = 0; nt < 2; ++nt)
            #pragma unroll
            for (int e = 0; e < 16; ++e) acc[nt][e] = 0.f;

        const int ob = w * 32 + li;   // output channel (D col)
        #pragma unroll
        for (int ks = 0; ks < 8; ++ks) {
            const int c8 = ks * 2 + hs;
            const bf16x8 bh = *(const bf16x8*)(wh + ((size_t)c8 * C2 + ob) * 8);
            const bf16x8 bl = *(const bf16x8*)(wl + ((size_t)c8 * C2 + ob) * 8);
            #pragma unroll
            for (int nt = 0; nt < 2; ++nt) {
                const bf16x8 a = *(const bf16x8*)&Xb[c8][nt * 32 + li][0];
                acc[nt] = __builtin_amdgcn_mfma_f32_32x32x16_bf16(a, bh, acc[nt], 0, 0, 0);
                acc[nt] = __builtin_amdgcn_mfma_f32_32x32x16_bf16(a, bl, acc[nt], 0, 0, 0);
            }
        }

        const float bb = bias[ob] * (z ? 1.0f : RCP_LN2);
        #pragma unroll
        for (int nt = 0; nt < 2; ++nt)
            #pragma unroll
            for (int r = 0; r < 16; ++r) {
                const int n = n0 + nt * 32 + (r & 3) + 8 * (r >> 2) + 4 * hs;
                out[((size_t)b * NPIX + n) * C2 + ob] = f2bf(acc[nt][r] + bb);
            }
    } else {
        // ---------------- V : out [b][o][n], n-tile 32 ---------------------
        u16 (*Xv)[32][8] = (u16 (*)[32][8])(&Xb[0][0][0]);
        const int n0 = blockIdx.x * 64 + (z - 2) * 32;
        {
            const int sn = t & 31;
            const int cg = t >> 5;
            const float* xb = motion + (size_t)b * C * NPIX + n0 + sn;
            #pragma unroll
            for (int r = 0; r < 4; ++r) {
                const int c8 = r * 8 + cg;
                union { bf16_t e[8]; uint4 u4; } cv;
                #pragma unroll
                for (int j = 0; j < 8; ++j)
                    cv.e[j] = (bf16_t)xb[(size_t)(c8 * 8 + j) * NPIX];
                *(uint4*)&Xv[c8][sn][0] = cv.u4;
            }
        }
        __syncthreads();

        f32x16 acc[2];
        #pragma unroll
        for (int ot = 0; ot < 2; ++ot)
            #pragma unroll
            for (int e = 0; e < 16; ++e) acc[ot][e] = 0.f;

        #pragma unroll
        for (int ks = 0; ks < 16; ++ks) {
            const int c8 = ks * 2 + hs;
            const bf16x8 xf = *(const bf16x8*)&Xv[c8][li][0];
            #pragma unroll
            for (int ot = 0; ot < 2; ++ot) {
                const int o = w * 64 + ot * 32 + li;
                const bf16x8 ah = *(const bf16x8*)(wvh + ((size_t)c8 * C + o) * 8);
                const bf16x8 al = *(const bf16x8*)(wvl + ((size_t)c8 * C + o) * 8);
                acc[ot] = __builtin_amdgcn_mfma_f32_32x32x16_bf16(ah, xf, acc[ot], 0, 0, 0);
                acc[ot] = __builtin_amdgcn_mfma_f32_32x32x16_bf16(al, xf, acc[ot], 0, 0, 0);
            }
        }

        #pragma unroll
        for (int ot = 0; ot < 2; ++ot)
            #pragma unroll
            for (int g = 0; g < 4; ++g) {
                const int orow = w * 64 + ot * 32 + 8 * g + 4 * hs;
                const float4 b4 = *(const float4*)&bv[orow];
                const size_t base = ((size_t)b * C + orow) * NPIX + n0 + li;
                vout[base]            = f2bf(acc[ot][g * 4 + 0] + b4.x);
                vout[base + NPIX]     = f2bf(acc[ot][g * 4 + 1] + b4.y);
                vout[base + 2 * NPIX] = f2bf(acc[ot][g * 4 + 2] + b4.z);
                vout[base + 3 * NPIX] = f2bf(acc[ot][g * 4 + 3] + b4.w);
            }
    }
}

// ----------------------------- MFMA attention v4 ---------------------------
// Same math/layout as v3, but ALL hot-loop LDS addresses are hoisted to
// per-lane base pointers + compile-time immediates:
//   K-read:  8 ptrs, +cur*8192B          V-read: 4 ptrs, +ct*2048B +cur*16KB
//   K-write: 1 ptr,  +q*4096B +nxt*8192B V-write: 2 ptrs, +q*4096B +nxt*16KB
// (x = rc&15 = li>>1 and c&1 = li&1 are ct/q-invariant -> offsets fold.)
// Main loop manually unrolled x2 so `cur` is a compile-time constant.
struct SR { uint4 k[2]; uint4 v[4]; };

#define ATTN_STEP(CUR, ITR)                                                    \
  {                                                                            \
    if ((ITR) < 63) {                                                          \
      *(uint4*)(kwp + ((CUR) ^ 1) * 4096)        = R.k[0];                     \
      *(uint4*)(kwp + ((CUR) ^ 1) * 4096 + 2048) = R.k[1];                     \
      _Pragma("unroll")                                                        \
      for (int q = 0; q < 4; ++q) {                                            \
        *(uint2*)(vw0 + ((CUR) ^ 1) * 8192 + q * 2048) =                       \
            make_uint2(R.v[q].x, R.v[q].y);                                    \
        *(uint2*)(vw1 + ((CUR) ^ 1) * 8192 + q * 2048) =                       \
            make_uint2(R.v[q].z, R.v[q].w);                                    \
      }                                                                        \
      if ((ITR) < 62) {                                                        \
        _Pragma("unroll")                                                      \
        for (int q = 0; q < 2; ++q) R.k[q] = *(const uint4*)(kgt + 2048 * q);  \
        _Pragma("unroll")                                                      \
        for (int q = 0; q < 4; ++q)                                            \
          R.v[q] = *(const uint4*)(vgt + (size_t)(64 * q) * NPIX);             \
        kgt += 4096; vgt += 32;                                                \
      }                                                                        \
    }                                                                          \
    f32x16 s;                                                                  \
    _Pragma("unroll") for (int e = 0; e < 16; ++e) s[e] = 0.f;                 \
    __builtin_amdgcn_s_setprio(1);                                             \
    _Pragma("unroll")                                                          \
    for (int ct = 0; ct < 8; ++ct) {                                           \
      const bf16x8 kf = *(const bf16x8*)(krd[ct] + (CUR) * 4096);              \
      s = __builtin_amdgcn_mfma_f32_32x32x16_bf16(kf, qf[ct], s, 0, 0, 0);     \
    }                                                                          \
    __builtin_amdgcn_s_setprio(0);                                             \
    u32 pk[8];                                                                 \
    _Pragma("unroll")                                                          \
    for (int n = 0; n < 8; ++n) {                                              \
      const float p0 = exp2f(s[2 * n]);                                        \
      const float p1 = exp2f(s[2 * n + 1]);                                    \
      ssl += p0 + p1;                                                          \
      union { bf16_t e[2]; u32 u; } cv;                                        \
      cv.e[0] = (bf16_t)p0; cv.e[1] = (bf16_t)p1;                              \
      pk[n] = cv.u;                                                            \
    }                                                                          \
    bf16x8 pf[2];                                                              \
    _Pragma("unroll")                                                          \
    for (int seg = 0; seg < 2; ++seg) {                                        \
      const u32 A0 = pk[4 * seg + 0], A1 = pk[4 * seg + 1];                    \
      const u32 A2 = pk[4 * seg + 2], A3 = pk[4 * seg + 3];                    \
      const u32 own0 = hs ? A2 : A0, own1 = hs ? A3 : A1;                      \
      const u32 snd0 = hs ? A0 : A2, snd1 = hs ? A1 : A3;                      \
      const u32 rcv0 = (u32)__shfl_xor((int)snd0, 32, 64);                     \
      const u32 rcv1 = (u32)__shfl_xor((int)snd1, 32, 64);                     \
      union { u32 u[4]; bf16x8 v; } bb2;                                       \
      bb2.u[0] = hs ? rcv0 : own0; bb2.u[1] = hs ? rcv1 : own1;                \
      bb2.u[2] = hs ? own0 : rcv0; bb2.u[3] = hs ? own1 : rcv1;                \
      pf[seg] = bb2.v;                                                         \
    }                                                                          \
    __builtin_amdgcn_s_setprio(1);                                             \
    _Pragma("unroll")                                                          \
    for (int ct = 0; ct < 8; ++ct) {                                           \
      union { uint2 g[2]; bf16x8 v8; } u0;                                     \
      u0.g[0] = *(const uint2*)(vr00 + (CUR) * 8192 + ct * 1024);              \
      u0.g[1] = *(const uint2*)(vr01 + (CUR) * 8192 + ct * 1024);              \
      oacc[ct] = __builtin_amdgcn_mfma_f32_32x32x16_bf16(u0.v8, pf[0], oacc[ct], 0, 0, 0); \
      union { uint2 g[2]; bf16x8 v8; } u1;                                     \
      u1.g[0] = *(const uint2*)(vr10 + (CUR) * 8192 + ct * 1024);              \
      u1.g[1] = *(const uint2*)(vr11 + (CUR) * 8192 + ct * 1024);              \
      oacc[ct] = __builtin_amdgcn_mfma_f32_32x32x16_bf16(u1.v8, pf[1], oacc[ct], 0, 0, 0); \
    }                                                                          \
    __builtin_amdgcn_s_setprio(0);                                             \
    __syncthreads();                                                           \
  }

__global__ __launch_bounds__(256, 2)
void attn_mfma4(const u16* __restrict__ qt,   // [BS][NPIX][C2] (pre-scaled 1/ln2)
                const u16* __restrict__ kt,   // [BS][NPIX][C2]
                const u16* __restrict__ vn,   // [BS][C][NPIX]
                float* __restrict__ opart0,   // partial O, j-half 0 (fuse slot)
                float* __restrict__ opart1,   // partial O, j-half 1 (out slot)
                float* __restrict__ sbuf) {   // [2][BS][NPIX] partial sums
    // [Kb0 | Kb1 | Vb0 | Vb1] : 8KB + 8KB + 16KB + 16KB = 48KB
    __shared__ __align__(16) u16 lds[24576];

    const int t  = threadIdx.x;
    const int w  = t >> 6;
    const int li = t & 31;
    const int hs = (t >> 5) & 1;

    const int b  = blockIdx.x & 7;                 // batch <-> XCD affinity
    const int it = (blockIdx.x >> 3) & 31;
    const int h  = blockIdx.x >> 8;                // j-half
    const int i0 = it * 128;
    const int iw = i0 + w * 32 + li;
    const int j0 = h * 2048;

    u16* const Kb0 = lds;
    u16* const Vb0 = lds + 8192;

    // ---- hoisted LDS write pointers (q/ct-invariant parts pre-folded)
    u16* const kwp = Kb0 + (t >> 4) * 128 + (((t & 15) ^ ((t >> 4) & 15)) * 8);
    const int q8w = ((t >> 2) & 1) * 8 + (t & 3) * 2;
    const int xw  = (t >> 3) & 15;
    u16* const vw0 = Vb0 + (t >> 3) * 64 + ((q8w    ) ^ xw) * 4;
    u16* const vw1 = Vb0 + (t >> 3) * 64 + ((q8w + 1) ^ xw) * 4;

    // ---- hoisted LDS read pointers
    const u16* krd[8];
    #pragma unroll
    for (int ct = 0; ct < 8; ++ct)
        krd[ct] = Kb0 + li * 128 + (((ct * 2 + hs) ^ (li & 15)) * 8);
    const int xr  = li >> 1;
    const int cbr = (li & 1) * 8 + hs * 2;
    const u16* const vr00 = Vb0 + xr * 64 + ((cbr    ) ^ xr) * 4;
    const u16* const vr01 = Vb0 + xr * 64 + ((cbr + 1) ^ xr) * 4;
    const u16* const vr10 = Vb0 + xr * 64 + ((cbr + 4) ^ xr) * 4;
    const u16* const vr11 = Vb0 + xr * 64 + ((cbr + 5) ^ xr) * 4;

    // ---- Q fragments (persistent)
    bf16x8 qf[8];
    {
        const u16* qp = qt + ((size_t)b * NPIX + iw) * C2 + hs * 8;
        #pragma unroll
        for (int ct = 0; ct < 8; ++ct) qf[ct] = *(const bf16x8*)(qp + ct * 16);
    }

    f32x16 oacc[8];
    #pragma unroll
    for (int ct = 0; ct < 8; ++ct)
        #pragma unroll
        for (int e = 0; e < 16; ++e) oacc[ct][e] = 0.f;

    // ---- advancing global staging pointers
    const u16* kgt = kt + ((size_t)b * NPIX + j0) * C2 + t * 8;
    const u16* vgt = vn + (size_t)b * C * NPIX + j0 + (t & 3) * 8
                        + (size_t)(t >> 2) * NPIX;

    SR R;
    // jt = 0
    #pragma unroll
    for (int q = 0; q < 2; ++q) R.k[q] = *(const uint4*)(kgt + 2048 * q);
    #pragma unroll
    for (int q = 0; q < 4; ++q) R.v[q] = *(const uint4*)(vgt + (size_t)(64 * q) * NPIX);
    kgt += 4096; vgt += 32;
    // write buf0
    *(uint4*)(kwp)        = R.k[0];
    *(uint4*)(kwp + 2048) = R.k[1];
    #pragma unroll
    for (int q = 0; q < 4; ++q) {
        *(uint2*)(vw0 + q * 2048) = make_uint2(R.v[q].x, R.v[q].y);
        *(uint2*)(vw1 + q * 2048) = make_uint2(R.v[q].z, R.v[q].w);
    }
    // jt = 1
    #pragma unroll
    for (int q = 0; q < 2; ++q) R.k[q] = *(const uint4*)(kgt + 2048 * q);
    #pragma unroll
    for (int q = 0; q < 4; ++q) R.v[q] = *(const uint4*)(vgt + (size_t)(64 * q) * NPIX);
    kgt += 4096; vgt += 32;
    __syncthreads();

    float ssl = 0.f;
    for (int it2 = 0; it2 < 32; ++it2) {
        ATTN_STEP(0, it2 * 2)
        ATTN_STEP(1, it2 * 2 + 1)
    }

    ssl += __shfl_xor(ssl, 32, 64);
    if (hs == 0) sbuf[((size_t)h * BS + b) * NPIX + iw] = ssl;

    float* op = h ? opart1 : opart0;
    #pragma unroll
    for (int ct = 0; ct < 8; ++ct) {
        #pragma unroll
        for (int r = 0; r < 16; ++r) {
            const int c = ct * 32 + (r & 3) + 8 * (r >> 2) + 4 * hs;
            op[((size_t)b * C + c) * NPIX + iw] = oacc[ct][r];
        }
    }
}

// ---- merge: out = (O1+O2)/(s1+s2); fuse = out*motion -----------------------
__global__ __launch_bounds__(256)
void attn_merge(float* __restrict__ fuse,    // in: O1 partial, out: fuse_out
                float* __restrict__ outp,    // in: O2 partial, out: out
                const float* __restrict__ motion,
                const float* __restrict__ sbuf) {
    const size_t idx = ((size_t)blockIdx.x * 256 + threadIdx.x) * 4;
    const int n = (int)(idx & (NPIX - 1));
    const int b = (int)(idx >> 20);
    const float4 o1 = *(const float4*)(fuse + idx);
    const float4 o2 = *(const float4*)(outp + idx);
    const float4 sa = *(const float4*)(sbuf + (size_t)b * NPIX + n);
    const float4 sb = *(const float4*)(sbuf + (size_t)(BS + b) * NPIX + n);
    float4 o;
    o.x = (o1.x + o2.x) / (sa.x + sb.x);
    o.y = (o1.y + o2.y) / (sa.y + sb.y);
    o.z = (o1.z + o2.z) / (sa.z + sb.z);
    o.w = (o1.w + o2.w) / (sa.w + sb.w);
    const float4 mv = *(const float4*)(motion + idx);
    *(float4*)(outp + idx) = o;
    *(float4*)(fuse + idx) = make_float4(o.x * mv.x, o.y * mv.y, o.z * mv.z, o.w * mv.w);
}

extern "C" void kernel_launch(void* const* d_in, const int* in_sizes, int n_in,
                              void* d_out, int out_size, void* d_ws, size_t ws_size,
                              hipStream_t stream) {
    const float* a1     = (const float*)d_in[0];  // appearance_1 -> k
    const float* a2     = (const float*)d_in[1];  // appearance_2 -> q
    const float* motion = (const float*)d_in[2];  // -> v, and fuse multiplier
    const float* Wq = (const float*)d_in[3];
    const float* bq = (const float*)d_in[4];
    const float* Wk = (const float*)d_in[5];
    const float* bk = (const float*)d_in[6];
    const float* Wv = (const float*)d_in[7];
    const float* bv = (const float*)d_in[8];

    float* outp = (float*)d_out;  // [fuse_out | out]
    float* slot0 = outp;                              // fuse slot / O1 partial
    float* slot1 = outp + (size_t)BS * C * NPIX;      // out slot  / O2 partial

    // workspace: QT (8MB) | KT (8MB) | V (16MB) | sbuf (256KB) | W frags
    u16* qws = (u16*)d_ws;
    u16* kws = qws + (size_t)BS * C2 * NPIX;
    u16* vws = kws + (size_t)BS * C2 * NPIX;
    float* sbuf = (float*)(vws + (size_t)BS * C * NPIX);
    u16* wqh = (u16*)(sbuf + (size_t)2 * BS * NPIX);
    u16* wql = wqh + C2 * C2;
    u16* wkh = wql + C2 * C2;
    u16* wkl = wkh + C2 * C2;
    u16* wvh = wkl + C2 * C2;
    u16* wvl = wvh + C * C;

    const dim3 blk(256);
    prep_w<<<dim3(32, 3), blk, 0, stream>>>(Wq, Wk, Wv, wqh, wql, wkh, wkl, wvh, wvl);
    proj_all<<<dim3(NPIX / 64, BS, 4), blk, 0, stream>>>(
        wqh, wql, wkh, wkl, wvh, wvl, bq, bk, bv, a2, a1, motion, qws, kws, vws);

    attn_mfma4<<<dim3(512), blk, 0, stream>>>(qws, kws, vws, slot0, slot1, sbuf);

    attn_merge<<<dim3((BS * C * NPIX) / 1024), blk, 0, stream>>>(
        slot0, slot1, motion, sbuf);
}